// Round 17
// baseline (218.390 us; speedup 1.0000x reference)
//
#include <hip/hip_runtime.h>
#include <hip/hip_bf16.h>
#include <math.h>

// x[32,512,64,64] f32; w1[32,512] f32; w2[512,32] f32.
// Bit-replication of the numpy-fp32 reference pipeline (round-4 PASSED, absmax 0.0):
//   y = np.mean(x,(2,3))             -> numpy pairwise_sum (128-blocks, 8 accums, tree)
//   h = relu(np.einsum('bc,rc->br')) -> SSE sum-of-products (mod-4 lanes, (L0+L1)+(L2+L3))
//   s = 1/(1+np.exp(-z))             -> correctly-rounded fp32 exp via fp64, fp32 add/div
//   idx = argsort(-s, stable)[:, :256]; out = take_along_axis(x, idx)
// Round 17: TWO graph nodes (was 3). Probes triangulated ~17us per-node overhead
// (pool marginal 38=17+21warm, gather 38.7=17+21, se 19=17+2). Both grid-sync
// fusion attempts (manual barrier r14/15, cooperative r16) failed to launch, so
// instead se is fused INTO gather via redundant per-block recompute: each of the
// 512 gather blocks recomputes its batch's scores+ranks from g_y (verbatim r12
// arithmetic -> identical bits in every block), keeps the rank->channel map in
// LDS, then copies its 2 planes. No inter-block dependency; dispatch-order-safe.

#define C1 512
#define C2 256
#define CMID 32
#define HW 4096   // 64*64
#define B 32

typedef float f32x4 __attribute__((ext_vector_type(4)));

__device__ float g_y[B * C1];     // pooled means, fp32 (numpy-bit-exact)

// ---------------- Kernel 1: numpy-pairwise mean, one wave per channel ----------------
// Verified r8 body (bit-exact, at HBM floor). Lane-pair (2m,2m+1) owns 128-block m;
// lane holds accumulators r[4h..4h+3]; chain r_j += a[8i+j] (i=1..15); combine
// ((r0+r1)+(r2+r3))+((r4+r5)+(r6+r7)) then perfect tree over 32 blocks, all via
// xor-shuffles (fp32 add bitwise-commutative -> canonical bits in every lane).
__global__ __launch_bounds__(256) void pool_np_kernel(const float* __restrict__ x) {
    int bc = blockIdx.x * 4 + (threadIdx.x >> 6);   // channel 0..16383
    int L = threadIdx.x & 63;
    const float* a = x + (size_t)bc * HW;
    const float* base = a + (L >> 1) * 128 + (L & 1) * 4;
    f32x4 r = *(const f32x4*)base;
#pragma unroll
    for (int i = 1; i < 16; ++i) {
        f32x4 v = *(const f32x4*)(base + 8 * i);
        r.x = __fadd_rn(r.x, v.x);
        r.y = __fadd_rn(r.y, v.y);
        r.z = __fadd_rn(r.z, v.z);
        r.w = __fadd_rn(r.w, v.w);
    }
    float s = __fadd_rn(__fadd_rn(r.x, r.y), __fadd_rn(r.z, r.w));
    s = __fadd_rn(s, __shfl_xor(s, 1));
    s = __fadd_rn(s, __shfl_xor(s, 2));
    s = __fadd_rn(s, __shfl_xor(s, 4));
    s = __fadd_rn(s, __shfl_xor(s, 8));
    s = __fadd_rn(s, __shfl_xor(s, 16));
    s = __fadd_rn(s, __shfl_xor(s, 32));
    if (L == 0) g_y[bc] = __fdiv_rn(s, 4096.0f);
}

// ---------------- Kernel 2: fused SE-MLP + rank (per-block recompute) + gather ------
// 512 blocks x 512 threads; block handles planes {2*blockIdx, 2*blockIdx+1},
// both in batch b = blockIdx>>7. Scores/ranks recomputed redundantly per block
// from g_y with the r12-verified arithmetic -> bit-identical in every block.
__global__ __launch_bounds__(512) void se_gather_kernel(const float* __restrict__ x,
                                                        const float* __restrict__ w1,
                                                        const float* __restrict__ w2,
                                                        float* __restrict__ out) {
    int t = threadIdx.x;             // 0..511
    int b = blockIdx.x >> 7;         // batch 0..31 (128 blocks per batch)
    __shared__ float ys[C1];
    __shared__ float hs[CMID];
    __shared__ float ss[C1];
    __shared__ int   idx_l[C2];      // rank -> channel, block-local

    // w2 row into registers (r12-verified layer-2 source)
    f32x4 w2r[8];
#pragma unroll
    for (int i = 0; i < 8; ++i)
        w2r[i] = ((const f32x4*)(w2 + t * CMID))[i];

    ys[t] = g_y[b * C1 + t];
    __syncthreads();

    // Layer 1: 32 rows x 4 independent SSE chains (numpy L0..L3), w1 from global
    // (L2/L3-cached; r8/r16-verified path).
    if (t < CMID * 4) {
        int row = t >> 2, k = t & 3;
        const float* v = w1 + row * C1;
        float Lk = 0.f;
#pragma unroll
        for (int c = 0; c < C1; c += 8) {
            Lk = __fadd_rn(Lk, __fmul_rn(ys[c + k],     v[c + k]));
            Lk = __fadd_rn(Lk, __fmul_rn(ys[c + 4 + k], v[c + 4 + k]));
        }
        Lk = __fadd_rn(Lk, __shfl_xor(Lk, 1));   // (L0+L1),(L2+L3)
        Lk = __fadd_rn(Lk, __shfl_xor(Lk, 2));
        if (k == 0) hs[row] = Lk > 0.0f ? Lk : 0.0f;   // np.maximum(z, 0)
    }
    __syncthreads();

    // Layer 2: numpy SSE dot over CMID=32 (registers + LDS hs), then sigmoid
    {
        float L0 = 0.f, L1 = 0.f, L2 = 0.f, L3 = 0.f;
#pragma unroll
        for (int i = 0; i < 8; i += 2) {
            L0 = __fadd_rn(L0, __fmul_rn(hs[i * 4 + 0], w2r[i].x));
            L1 = __fadd_rn(L1, __fmul_rn(hs[i * 4 + 1], w2r[i].y));
            L2 = __fadd_rn(L2, __fmul_rn(hs[i * 4 + 2], w2r[i].z));
            L3 = __fadd_rn(L3, __fmul_rn(hs[i * 4 + 3], w2r[i].w));
            L0 = __fadd_rn(L0, __fmul_rn(hs[i * 4 + 4], w2r[i + 1].x));
            L1 = __fadd_rn(L1, __fmul_rn(hs[i * 4 + 5], w2r[i + 1].y));
            L2 = __fadd_rn(L2, __fmul_rn(hs[i * 4 + 6], w2r[i + 1].z));
            L3 = __fadd_rn(L3, __fmul_rn(hs[i * 4 + 7], w2r[i + 1].w));
        }
        float z = __fadd_rn(__fadd_rn(L0, L1), __fadd_rn(L2, L3));
        float e = (float)exp((double)(-z));      // correctly-rounded fp32 exp
        ss[t] = __fdiv_rn(1.0f, __fadd_rn(1.0f, e));
    }
    __syncthreads();

    // stable argsort(-s): rank = #{s' > s} + #{equal with smaller index}
    {
        float sc = ss[t];
        int rank = 0;
#pragma unroll 8
        for (int c = 0; c < C1; ++c) {
            float v = ss[c];
            rank += (int)((v > sc) || (v == sc && c < t));
        }
        if (rank < C2) idx_l[rank] = t;          // block-local map
    }
    __syncthreads();

    // Gather: 2 planes per block; plane = 1024 f32x4 units -> 2 units/thread.
#pragma unroll
    for (int q = 0; q < 2; ++q) {
        int bid = blockIdx.x * 2 + q;            // plane 0..1023 (b*C2 + r)
        int c = idx_l[bid & 255];                // rank within batch
        const f32x4* src = (const f32x4*)(x + ((size_t)(b * C1 + c)) * HW);
        f32x4* dst = (f32x4*)(out + (size_t)bid * HW);
        f32x4 v0 = src[t];
        f32x4 v1 = src[t + 512];
        __builtin_nontemporal_store(v0, &dst[t]);
        __builtin_nontemporal_store(v1, &dst[t + 512]);
    }
}

extern "C" void kernel_launch(void* const* d_in, const int* in_sizes, int n_in,
                              void* d_out, int out_size, void* d_ws, size_t ws_size,
                              hipStream_t stream) {
    const float* x  = (const float*)d_in[0];
    const float* w1 = (const float*)d_in[1];
    const float* w2 = (const float*)d_in[2];
    float* out = (float*)d_out;

    pool_np_kernel<<<B * C1 / 4, 256, 0, stream>>>(x);
    se_gather_kernel<<<B * C2 / 2, 512, 0, stream>>>(x, w1, w2, out);
}

// Round 18
// 90.447 us; speedup vs baseline: 2.4146x; 2.4146x over previous
//
#include <hip/hip_runtime.h>
#include <hip/hip_bf16.h>
#include <math.h>

// x[32,512,64,64] f32; w1[32,512] f32; w2[512,32] f32.
// Bit-replication of the numpy-fp32 reference pipeline (round-4 PASSED, absmax 0.0):
//   y = np.mean(x,(2,3))             -> numpy pairwise_sum (128-blocks, 8 accums, tree)
//   h = relu(np.einsum('bc,rc->br')) -> SSE sum-of-products (mod-4 lanes, (L0+L1)+(L2+L3))
//   s = 1/(1+np.exp(-z))             -> correctly-rounded fp32 exp via fp64, fp32 add/div
//   idx = argsort(-s, stable)[:, :256]; out = take_along_axis(x, idx)
// Round 18: r17 counters proved se is ~18us of VALU-bound device work (launch
// overhead is small; fusion arc was misattribution). Fix: parallelize se 8x.
// Rank = sum of indicator bits -> split the candidate axis across 8 blocks per
// batch, integer atomicAdd partial ranks (commutative => deterministic & exact).
// Pool zeroes g_rank each call (replay-safe). Gather inverts rank->channel via
// one coalesced read + LDS match. Pool/gather bodies verbatim (at BW floors).

#define C1 512
#define C2 256
#define CMID 32
#define HW 4096   // 64*64
#define B 32
#define W1PAD 516  // 512 + 4-float pad

typedef float f32x4 __attribute__((ext_vector_type(4)));

__device__ float g_y[B * C1];      // pooled means, fp32 (numpy-bit-exact)
__device__ int   g_rank[B * C1];   // per-channel rank (accumulated via atomicAdd)

// ---------------- Kernel 1: numpy-pairwise mean + g_rank zeroing ----------------
// Verified r8 body (bit-exact, at HBM floor). Also re-zeroes g_rank every call
// (first 64 blocks), making the atomic rank accumulation replay-deterministic.
__global__ __launch_bounds__(256) void pool_np_kernel(const float* __restrict__ x) {
    if (blockIdx.x < 64) g_rank[blockIdx.x * 256 + threadIdx.x] = 0;

    int bc = blockIdx.x * 4 + (threadIdx.x >> 6);   // channel 0..16383
    int L = threadIdx.x & 63;
    const float* a = x + (size_t)bc * HW;
    const float* base = a + (L >> 1) * 128 + (L & 1) * 4;
    f32x4 r = *(const f32x4*)base;
#pragma unroll
    for (int i = 1; i < 16; ++i) {
        f32x4 v = *(const f32x4*)(base + 8 * i);
        r.x = __fadd_rn(r.x, v.x);
        r.y = __fadd_rn(r.y, v.y);
        r.z = __fadd_rn(r.z, v.z);
        r.w = __fadd_rn(r.w, v.w);
    }
    float s = __fadd_rn(__fadd_rn(r.x, r.y), __fadd_rn(r.z, r.w));
    s = __fadd_rn(s, __shfl_xor(s, 1));    // lane0 chain + lane1 chain
    s = __fadd_rn(s, __shfl_xor(s, 2));    // perfect tree over the 32 blocks
    s = __fadd_rn(s, __shfl_xor(s, 4));
    s = __fadd_rn(s, __shfl_xor(s, 8));
    s = __fadd_rn(s, __shfl_xor(s, 16));
    s = __fadd_rn(s, __shfl_xor(s, 32));
    if (L == 0) g_y[bc] = __fdiv_rn(s, 4096.0f);
}

// ---------------- Kernel 2: SE MLP (r12-verified bits) + PARTIAL rank ----------------
// 256 blocks x 512 threads; block (b = bid>>3, j = bid&7). Every block of batch b
// recomputes ss[512] bit-identically; block j accumulates ranks over candidate
// chunk c in [j*64, j*64+64) via atomicAdd (int sum -> order-independent).
__global__ __launch_bounds__(512) void se_rank_kernel(const float* __restrict__ w1,
                                                      const float* __restrict__ w2) {
    int b = blockIdx.x >> 3;
    int j = blockIdx.x & 7;
    int t = threadIdx.x;       // 0..511
    __shared__ float ys[C1];
    __shared__ float hs[CMID];
    __shared__ float ss[C1];
    __shared__ float w1s[CMID * W1PAD];   // 66 KB staged w1 (r12-verified path)

    f32x4 w2r[8];
#pragma unroll
    for (int i = 0; i < 8; ++i)
        w2r[i] = ((const f32x4*)(w2 + t * CMID))[i];

#pragma unroll
    for (int i = 0; i < 8; ++i) {
        int u = i * 512 + t;               // f32x4 unit index in w1
        int row  = u >> 7;
        int col4 = u & 127;
        f32x4 v = ((const f32x4*)w1)[u];
        *(f32x4*)&w1s[row * W1PAD + col4 * 4] = v;
    }
    ys[t] = g_y[b * C1 + t];
    __syncthreads();

    // Layer 1: 32 rows x 4 independent SSE chains (numpy L0..L3), thread = (row,k)
    if (t < CMID * 4) {
        int row = t >> 2, k = t & 3;
        const float* wr = &w1s[row * W1PAD];
        float Lk = 0.f;
#pragma unroll
        for (int c = 0; c < C1; c += 8) {
            Lk = __fadd_rn(Lk, __fmul_rn(ys[c + k],     wr[c + k]));
            Lk = __fadd_rn(Lk, __fmul_rn(ys[c + 4 + k], wr[c + 4 + k]));
        }
        Lk = __fadd_rn(Lk, __shfl_xor(Lk, 1));   // (L0+L1),(L2+L3)
        Lk = __fadd_rn(Lk, __shfl_xor(Lk, 2));
        if (k == 0) hs[row] = Lk > 0.0f ? Lk : 0.0f;   // np.maximum(z, 0)
    }
    __syncthreads();

    // Layer 2: numpy SSE dot over CMID=32 (registers + LDS hs), then sigmoid
    {
        float L0 = 0.f, L1 = 0.f, L2 = 0.f, L3 = 0.f;
#pragma unroll
        for (int i = 0; i < 8; i += 2) {
            L0 = __fadd_rn(L0, __fmul_rn(hs[i * 4 + 0], w2r[i].x));
            L1 = __fadd_rn(L1, __fmul_rn(hs[i * 4 + 1], w2r[i].y));
            L2 = __fadd_rn(L2, __fmul_rn(hs[i * 4 + 2], w2r[i].z));
            L3 = __fadd_rn(L3, __fmul_rn(hs[i * 4 + 3], w2r[i].w));
            L0 = __fadd_rn(L0, __fmul_rn(hs[i * 4 + 4], w2r[i + 1].x));
            L1 = __fadd_rn(L1, __fmul_rn(hs[i * 4 + 5], w2r[i + 1].y));
            L2 = __fadd_rn(L2, __fmul_rn(hs[i * 4 + 6], w2r[i + 1].z));
            L3 = __fadd_rn(L3, __fmul_rn(hs[i * 4 + 7], w2r[i + 1].w));
        }
        float z = __fadd_rn(__fadd_rn(L0, L1), __fadd_rn(L2, L3));
        float e = (float)exp((double)(-z));      // correctly-rounded fp32 exp
        ss[t] = __fdiv_rn(1.0f, __fadd_rn(1.0f, e));
    }
    __syncthreads();

    // Partial stable-descending rank over candidate chunk [j*64, j*64+64):
    // rank_part = #{c in chunk : ss[c] > sc  or (ss[c]==sc and c < t)}
    {
        float sc = ss[t];
        int c0 = j * 64;
        int rank = 0;
#pragma unroll 16
        for (int c = c0; c < c0 + 64; ++c) {
            float v = ss[c];
            rank += (int)((v > sc) || (v == sc && c < t));
        }
        atomicAdd(&g_rank[b * C1 + t], rank);   // int sum: order-independent
    }
}

// ---------------- Kernel 3: gather with in-block rank inversion ----------------
// 1024 blocks x 512 threads; block = plane (b = bid>>8, r = bid&255). One
// coalesced read of the batch's 512 ranks; the unique thread with rank==r
// publishes its channel; then the r15-verified 2-unit nt-store plane copy.
__global__ __launch_bounds__(512) void gather_kernel(const float* __restrict__ x,
                                                     float* __restrict__ out) {
    int bid = blockIdx.x;                      // plane 0..1023 (b*C2 + r)
    int b = bid >> 8;
    int r = bid & 255;
    int t = threadIdx.x;
    __shared__ int win;
    int rk = g_rank[b * C1 + t];
    if (rk == r) win = t;                      // exactly one match (ranks = perm)
    __syncthreads();
    int c = win;
    const f32x4* src = (const f32x4*)(x + ((size_t)(b * C1 + c)) * HW);
    f32x4* dst = (f32x4*)(out + (size_t)bid * HW);
    f32x4 v0 = src[t];
    f32x4 v1 = src[t + 512];
    __builtin_nontemporal_store(v0, &dst[t]);
    __builtin_nontemporal_store(v1, &dst[t + 512]);
}

extern "C" void kernel_launch(void* const* d_in, const int* in_sizes, int n_in,
                              void* d_out, int out_size, void* d_ws, size_t ws_size,
                              hipStream_t stream) {
    const float* x  = (const float*)d_in[0];
    const float* w1 = (const float*)d_in[1];
    const float* w2 = (const float*)d_in[2];
    float* out = (float*)d_out;

    pool_np_kernel<<<B * C1 / 4, 256, 0, stream>>>(x);
    se_rank_kernel<<<B * 8, 512, 0, stream>>>(w1, w2);
    gather_kernel<<<B * C2, 512, 0, stream>>>(x, out);
}